// Round 1
// baseline (222.311 us; speedup 1.0000x reference)
//
#pragma clang fp contract(off)
#include <hip/hip_runtime.h>
#include <hip/hip_bf16.h>

typedef unsigned long long u64;
typedef unsigned int u32;

#define NPTS   200000
#define MBOX   128
#define W64    3125      // NPTS / 64 exactly
#define W64P   3136      // padded row stride (u64 words)
#define SSAMP  256
#define AANCH  3
#define VOXELF 0.4f
#define PCSF   -75.2f

// ---------------- Kernel A: per-point 128-bit box masks -> row bitmaps ----------------
__global__ __launch_bounds__(256) void kA(const float* __restrict__ points,
                                          const float* __restrict__ boxes,
                                          u64* __restrict__ rowbits)
{
    __shared__ float sbx[128], sby[128], sr[128], sqx[128], sqy[128], srv[128];
    int tid = threadIdx.x;
    if (tid < 128) {
        float bx = boxes[tid*7+0], by = boxes[tid*7+1];
        float dx = boxes[tid*7+3], dy = boxes[tid*7+4];
        float hx = dx * 0.5f, hy = dy * 0.5f;
        float sq = hx*hx;
        sq = sq + hy*hy;
        float r = sqrtf(sq);                     // radii (GAMMA=1)
        sbx[tid] = bx; sby[tid] = by; sr[tid] = r;
        sqx[tid] = floorf((bx - PCSF) / VOXELF);
        sqy[tid] = floorf((by - PCSF) / VOXELF);
        srv[tid] = ceilf(r / VOXELF);            // rad_vox
    }
    __syncthreads();
    int w = blockIdx.x * 4 + (tid >> 6);
    if (w >= W64) return;
    int lane = tid & 63;
    int n = w * 64 + lane;
    float px = points[n*5+0], py = points[n*5+1];
    float cxn = floorf((px - PCSF) / VOXELF);
    float cyn = floorf((py - PCSF) / VOXELF);
    u64 lo = 0, hi = 0;
    bool voxany = false;
    for (int m = 0; m < 128; ++m) {
        float ddx = px - sbx[m], ddy = py - sby[m];
        float sq = ddx*ddx;
        sq = sq + ddy*ddy;
        float dis = sqrtf(sq);
        bool hit = (dis <= sr[m]);
        float aqx = fabsf(sqx[m] - cxn), aqy = fabsf(sqy[m] - cyn);
        bool vox = (aqx < srv[m]) & (aqy < srv[m]);
        voxany |= vox;
        if (m < 64) lo |= ((u64)hit) << m;
        else        hi |= ((u64)hit) << (m - 64);
    }
    if (!voxany) { lo = 0; hi = 0; }   // point_mask = circle & vmask
    for (int m = 0; m < 64; ++m) {
        u64 bal = __ballot(((lo >> m) & 1ull) != 0);
        if (lane == m) rowbits[(size_t)m * W64P + w] = bal;
    }
    for (int m = 0; m < 64; ++m) {
        u64 bal = __ballot(((hi >> m) & 1ull) != 0);
        if (lane == m) rowbits[(size_t)(m + 64) * W64P + w] = bal;
    }
}

// ---------------- Kernel B: inter[i][j] = popcount(row_i & row_j) ----------------
__global__ __launch_bounds__(256) void kB(const u64* __restrict__ rowbits,
                                          u32* __restrict__ inter)
{
    __shared__ u64 ldsI[W64];
    __shared__ u32 part[256];
    int i = blockIdx.x, tid = threadIdx.x;
    for (int w = tid; w < W64; w += 256) ldsI[w] = rowbits[(size_t)i * W64P + w];
    __syncthreads();
    int j = tid & 127, half = tid >> 7;
    const u64* rj = rowbits + (size_t)j * W64P;
    int wbeg = half ? 1563 : 0;
    int wend = half ? W64 : 1563;
    u32 acc = 0;
    #pragma unroll 4
    for (int w = wbeg; w < wend; ++w)
        acc += (u32)__popcll(ldsI[w] & rj[w]);
    part[tid] = acc;
    __syncthreads();
    if (tid < 128) inter[i * 128 + tid] = part[tid] + part[tid + 128];
}

// ---------------- Kernel C: miou argmax + sequential greedy grouping ----------------
__global__ __launch_bounds__(128) void kC(const u32* __restrict__ inter,
                                          const int* __restrict__ labels,
                                          const int* __restrict__ pNA,
                                          int* __restrict__ aidx_ws,
                                          float* __restrict__ out_anchor)
{
    __shared__ u32 cnt[128];
    __shared__ float mmax[128];
    __shared__ int midx[128];
    __shared__ int gof[128];
    __shared__ int gcnt[128];
    __shared__ int aidxL[128 * AANCH];
    int tid = threadIdx.x;
    cnt[tid] = inter[tid * 128 + tid];
    gof[tid] = -1; gcnt[tid] = 0;
    aidxL[tid*3+0] = -1; aidxL[tid*3+1] = -1; aidxL[tid*3+2] = -1;
    __syncthreads();
    int li = labels[tid];
    float best = 0.0f; int bidx = 0;
    for (int j = 0; j < 128; ++j) {
        if (j == tid) continue;
        if (labels[j] != li) continue;
        u32 I = inter[tid * 128 + j];
        long un = (long)cnt[tid] + (long)cnt[j] - (long)I;
        if (un > 0) {
            float v = (float)I / fmaxf((float)un, 1.0f);
            if (v > best) { best = v; bidx = j; }   // strict > : first-index argmax
        }
    }
    mmax[tid] = best; midx[tid] = bidx;
    __syncthreads();
    if (tid == 0) {
        int NA = *pNA;
        int ng = 0;
        for (int i = 0; i < 128; ++i) {
            int j  = midx[i];
            int gj = gof[j];
            int gjs = gj > 0 ? gj : 0;
            bool join = (mmax[i] > 0.5f) && (gj >= 0) && (gcnt[gjs] < NA);
            int tg = join ? gjs : ng;
            int ts = join ? gcnt[gjs] : 0;
            aidxL[tg * AANCH + ts] = i;
            gof[i] = tg;
            gcnt[tg] += 1;
            if (!join) ng += 1;
        }
    }
    __syncthreads();
    for (int t = tid; t < 128 * AANCH; t += 128) {
        aidx_ws[t] = aidxL[t];
        out_anchor[t] = (float)aidxL[t];   // int32 ref chunk read back as f32 values
    }
}

// ---------------- Kernel D: merged masks, ordered top-k selection, gather ----------------
__global__ __launch_bounds__(256) void kD(const u64* __restrict__ rowbits,
                                          const int* __restrict__ aidx_ws,
                                          const float* __restrict__ points,
                                          float* __restrict__ out)
{
    int g = blockIdx.x, tid = threadIdx.x;
    __shared__ u32 sl3[256], sl2[256], sl1[256];
    __shared__ u64 wtot[4];
    __shared__ u64 carried;
    float* outg = out + (size_t)g * SSAMP * 5;
    int a0 = aidx_ws[g*3+0], a1 = aidx_ws[g*3+1], a2 = aidx_ws[g*3+2];
    if (a0 < 0) {                      // invalid group -> all zeros
        for (int t = tid; t < SSAMP * 5; t += 256) outg[t] = 0.0f;
        return;
    }
    bool vA = (a0 >= 0), vB = (a1 >= 0), vC = (a2 >= 0);
    const u64* rA = rowbits + (size_t)(vA ? a0 : 0) * W64P;
    const u64* rB = rowbits + (size_t)(vB ? a1 : 0) * W64P;
    const u64* rC = rowbits + (size_t)(vC ? a2 : 0) * W64P;
    if (tid == 0) carried = 0;
    __syncthreads();
    int lane = tid & 63, wv = tid >> 6;
    const u64 M21 = (1ull << 21) - 1;
    for (int ch = 0; ch < 13; ++ch) {
        int w = ch * 256 + tid;
        bool inr = (w < W64);
        u64 a = (vA && inr) ? rA[w] : 0ull;
        u64 b = (vB && inr) ? rB[w] : 0ull;
        u64 c = (vC && inr) ? rC[w] : 0ull;
        u64 m3 = a & b & c;
        u64 any2 = (a & b) | (a & c) | (b & c);
        u64 m2 = any2 & ~m3;
        u64 m1 = (a | b | c) & ~any2;
        u64 p = ((u64)__popcll(m3) << 42) | ((u64)__popcll(m2) << 21) | (u64)__popcll(m1);
        u64 own = p;
        for (int d = 1; d < 64; d <<= 1) {       // inclusive wave scan (packed fields)
            u64 t = __shfl_up(p, d);
            if (lane >= d) p += t;
        }
        if (lane == 63) wtot[wv] = p;
        u64 excl = p - own;
        __syncthreads();
        u64 off = carried + excl;
        for (int k = 0; k < wv; ++k) off += wtot[k];
        u32 e3 = (u32)(off >> 42);
        u32 e2 = (u32)((off >> 21) & M21);
        u32 e1 = (u32)(off & M21);
        int nb = w * 64;
        u64 mm = m3; u32 o = e3;
        while (mm) { int b2 = __builtin_ctzll(mm); mm &= mm - 1; if (o < 256) sl3[o] = nb + b2; o++; }
        mm = m2; o = e2;
        while (mm) { int b2 = __builtin_ctzll(mm); mm &= mm - 1; if (o < 256) sl2[o] = nb + b2; o++; }
        mm = m1; o = e1;
        while (mm) { int b2 = __builtin_ctzll(mm); mm &= mm - 1; if (o < 256) sl1[o] = nb + b2; o++; }
        __syncthreads();
        if (tid == 0) carried += wtot[0] + wtot[1] + wtot[2] + wtot[3];
        __syncthreads();
    }
    u64 car = carried;
    u32 t3 = (u32)(car >> 42), t2 = (u32)((car >> 21) & M21), t1 = (u32)(car & M21);
    u32 s = (u32)tid;
    int n = -1;
    if (s < t3)                 n = (int)sl3[s];
    else if (s < t3 + t2)       n = (int)sl2[s - t3];
    else if (s < t3 + t2 + t1)  n = (int)sl1[s - t3 - t2];
    float v0=0.f, v1=0.f, v2=0.f, v3=0.f, v4=0.f;
    if (n >= 0) {
        const float* pp = points + (size_t)n * 5;
        v0 = pp[0]; v1 = pp[1]; v2 = pp[2]; v3 = pp[3]; v4 = pp[4];
    }
    outg[s*5+0] = v0; outg[s*5+1] = v1; outg[s*5+2] = v2;
    outg[s*5+3] = v3; outg[s*5+4] = v4;
}

extern "C" void kernel_launch(void* const* d_in, const int* in_sizes, int n_in,
                              void* d_out, int out_size, void* d_ws, size_t ws_size,
                              hipStream_t stream)
{
    const float* points = (const float*)d_in[0];
    const float* boxes  = (const float*)d_in[1];
    const int*   labels = (const int*)d_in[2];
    const int*   pNA    = (const int*)d_in[4];
    float* out = (float*)d_out;
    char* ws = (char*)d_ws;

    u64* rowbits = (u64*)ws;                                   // 128*3136*8 = 3,211,264 B
    u32* inter   = (u32*)(ws + (size_t)MBOX * W64P * 8);       // 65,536 B
    int* aidx    = (int*)(ws + (size_t)MBOX * W64P * 8 + 65536);

    float* out_anchor = out + (size_t)MBOX * SSAMP * 5;        // second output chunk

    kA<<<(W64 + 3) / 4, 256, 0, stream>>>(points, boxes, rowbits);
    kB<<<MBOX, 256, 0, stream>>>(rowbits, inter);
    kC<<<1, 128, 0, stream>>>(inter, labels, pNA, aidx, out_anchor);
    kD<<<MBOX, 256, 0, stream>>>(rowbits, aidx, points, out);
}

// Round 2
// 126.529 us; speedup vs baseline: 1.7570x; 1.7570x over previous
//
#pragma clang fp contract(off)
#include <hip/hip_runtime.h>
#include <hip/hip_bf16.h>

typedef unsigned long long u64;
typedef unsigned int u32;

#define NPTS   200000
#define MBOX   128
#define W64    3125      // NPTS / 64 exactly
#define W64C   3200      // padded column-major word count (25 chunks * 128)
#define NCH    25
#define CW     128       // words per kB chunk
#define ITILE  8         // i-rows per kB block
#define SSAMP  256
#define AANCH  3
#define VOXELF 0.4f
#define PCSF   -75.2f

// ---------------- Kernel A: per-point 128-bit box masks -> column-major bitmaps ----------------
// colbits[w*128 + m] = 64-bit word of row m covering points [w*64, w*64+64)
__global__ __launch_bounds__(256) void kA(const float* __restrict__ points,
                                          const float* __restrict__ boxes,
                                          u64* __restrict__ colbits,
                                          u32* __restrict__ inter)
{
    __shared__ float sbx[128], sby[128], sr[128], sqx[128], sqy[128], srv[128];
    int tid = threadIdx.x;
    // fold inter zero-init into this kernel (runs before kB in stream order)
    if (blockIdx.x < 64) inter[blockIdx.x * 256 + tid] = 0;
    if (tid < 128) {
        float bx = boxes[tid*7+0], by = boxes[tid*7+1];
        float dx = boxes[tid*7+3], dy = boxes[tid*7+4];
        float hx = dx * 0.5f, hy = dy * 0.5f;
        float sq = hx*hx;
        sq = sq + hy*hy;
        float r = sqrtf(sq);                     // radii (GAMMA=1)
        sbx[tid] = bx; sby[tid] = by; sr[tid] = r;
        sqx[tid] = floorf((bx - PCSF) / VOXELF);
        sqy[tid] = floorf((by - PCSF) / VOXELF);
        srv[tid] = ceilf(r / VOXELF);            // rad_vox
    }
    __syncthreads();
    int w = blockIdx.x * 4 + (tid >> 6);         // w in [0, W64C)
    int lane = tid & 63;
    int n = w * 64 + lane;
    bool valid = (n < NPTS);
    float px = 1e9f, py = 1e9f;
    if (valid) { px = points[n*5+0]; py = points[n*5+1]; }
    float cxn = floorf((px - PCSF) / VOXELF);
    float cyn = floorf((py - PCSF) / VOXELF);
    u64 lo = 0, hi = 0;
    bool voxany = false;
    for (int m = 0; m < 128; ++m) {
        float ddx = px - sbx[m], ddy = py - sby[m];
        float sq = ddx*ddx;
        sq = sq + ddy*ddy;
        float dis = sqrtf(sq);
        bool hit = (dis <= sr[m]);
        float aqx = fabsf(sqx[m] - cxn), aqy = fabsf(sqy[m] - cyn);
        bool vox = (aqx < srv[m]) & (aqy < srv[m]);
        voxany |= vox;
        if (m < 64) lo |= ((u64)hit) << m;
        else        hi |= ((u64)hit) << (m - 64);
    }
    if (!voxany) { lo = 0; hi = 0; }   // point_mask = circle & vmask
    u64 mylo = 0, myhi = 0;
    for (int m = 0; m < 64; ++m) {
        u64 bal = __ballot(((lo >> m) & 1ull) != 0);
        if (lane == m) mylo = bal;
    }
    for (int m = 0; m < 64; ++m) {
        u64 bal = __ballot(((hi >> m) & 1ull) != 0);
        if (lane == m) myhi = bal;
    }
    colbits[(size_t)w * 128 + lane]      = mylo;   // coalesced 512B per wave
    colbits[(size_t)w * 128 + 64 + lane] = myhi;
}

// ---------------- Kernel B: inter[i][j] += popcount(row_i & row_j), tiled bit-GEMM ----------------
__global__ __launch_bounds__(256) void kB(const u64* __restrict__ colbits,
                                          u32* __restrict__ inter)
{
    __shared__ u64 ldsI[CW * ITILE];   // [k][i] : 8KB
    __shared__ u32 part[128 * ITILE];  // 4KB
    int blk = blockIdx.x;
    int itile = blk / NCH, ch = blk % NCH;
    int i0 = itile * ITILE, w0 = ch * CW;
    int tid = threadIdx.x;
    for (int idx = tid; idx < CW * ITILE; idx += 256) {
        int w = idx >> 3, i = idx & 7;
        ldsI[idx] = colbits[(size_t)(w0 + w) * 128 + i0 + i];
    }
    __syncthreads();
    int j = tid & 127, dup = tid >> 7;     // dup splits the w-chunk in half
    u32 acc[ITILE] = {0,0,0,0,0,0,0,0};
    int kbeg = dup * (CW/2), kend = kbeg + (CW/2);
    #pragma unroll 2
    for (int k = kbeg; k < kend; ++k) {
        u64 rj = colbits[(size_t)(w0 + k) * 128 + j];   // coalesced across lanes
        #pragma unroll
        for (int i = 0; i < ITILE; ++i)
            acc[i] += (u32)__popcll(rj & ldsI[k * ITILE + i]);
    }
    if (dup == 1) {
        #pragma unroll
        for (int i = 0; i < ITILE; ++i) part[j * ITILE + i] = acc[i];
    }
    __syncthreads();
    if (dup == 0) {
        #pragma unroll
        for (int i = 0; i < ITILE; ++i)
            atomicAdd(&inter[(i0 + i) * 128 + j], acc[i] + part[j * ITILE + i]);
    }
}

// ---------------- Kernel C: miou argmax + sequential greedy grouping ----------------
__global__ __launch_bounds__(128) void kC(const u32* __restrict__ inter,
                                          const int* __restrict__ labels,
                                          const int* __restrict__ pNA,
                                          int* __restrict__ aidx_ws,
                                          float* __restrict__ out_anchor)
{
    __shared__ u32 cnt[128];
    __shared__ float mmax[128];
    __shared__ int midx[128];
    __shared__ int gof[128];
    __shared__ int gcnt[128];
    __shared__ int aidxL[128 * AANCH];
    int tid = threadIdx.x;
    cnt[tid] = inter[tid * 128 + tid];
    gof[tid] = -1; gcnt[tid] = 0;
    aidxL[tid*3+0] = -1; aidxL[tid*3+1] = -1; aidxL[tid*3+2] = -1;
    __syncthreads();
    int li = labels[tid];
    float best = 0.0f; int bidx = 0;
    for (int j = 0; j < 128; ++j) {
        if (j == tid) continue;
        if (labels[j] != li) continue;
        u32 I = inter[tid * 128 + j];
        long un = (long)cnt[tid] + (long)cnt[j] - (long)I;
        if (un > 0) {
            float v = (float)I / fmaxf((float)un, 1.0f);
            if (v > best) { best = v; bidx = j; }   // strict > : first-index argmax
        }
    }
    mmax[tid] = best; midx[tid] = bidx;
    __syncthreads();
    if (tid == 0) {
        int NA = *pNA;
        int ng = 0;
        for (int i = 0; i < 128; ++i) {
            int j  = midx[i];
            int gj = gof[j];
            int gjs = gj > 0 ? gj : 0;
            bool join = (mmax[i] > 0.5f) && (gj >= 0) && (gcnt[gjs] < NA);
            int tg = join ? gjs : ng;
            int ts = join ? gcnt[gjs] : 0;
            aidxL[tg * AANCH + ts] = i;
            gof[i] = tg;
            gcnt[tg] += 1;
            if (!join) ng += 1;
        }
    }
    __syncthreads();
    for (int t = tid; t < 128 * AANCH; t += 128) {
        aidx_ws[t] = aidxL[t];
        out_anchor[t] = (float)aidxL[t];   // int32 ref chunk read back as f32 values
    }
}

// ---------------- Kernel D: merged masks, ordered top-k selection, gather ----------------
__global__ __launch_bounds__(256) void kD(const u64* __restrict__ colbits,
                                          const int* __restrict__ aidx_ws,
                                          const float* __restrict__ points,
                                          float* __restrict__ out)
{
    int g = blockIdx.x, tid = threadIdx.x;
    __shared__ u32 sl3[256], sl2[256], sl1[256];
    __shared__ u64 wtot[4];
    __shared__ u64 carried;
    float* outg = out + (size_t)g * SSAMP * 5;
    int a0 = aidx_ws[g*3+0], a1 = aidx_ws[g*3+1], a2 = aidx_ws[g*3+2];
    if (a0 < 0) {                      // invalid group -> all zeros
        for (int t = tid; t < SSAMP * 5; t += 256) outg[t] = 0.0f;
        return;
    }
    bool vB = (a1 >= 0), vC = (a2 >= 0);
    int iA = a0, iB = vB ? a1 : 0, iC = vC ? a2 : 0;
    if (tid == 0) carried = 0;
    __syncthreads();
    int lane = tid & 63, wv = tid >> 6;
    const u64 M21 = (1ull << 21) - 1;
    for (int ch = 0; ch < 13; ++ch) {
        int w = ch * 256 + tid;
        bool inr = (w < W64);
        u64 a = 0, b = 0, c = 0;
        if (inr) {
            const u64* cw = colbits + (size_t)w * 128;
            a = cw[iA];
            b = vB ? cw[iB] : 0ull;
            c = vC ? cw[iC] : 0ull;
        }
        u64 m3 = a & b & c;
        u64 any2 = (a & b) | (a & c) | (b & c);
        u64 m2 = any2 & ~m3;
        u64 m1 = (a | b | c) & ~any2;
        u64 p = ((u64)__popcll(m3) << 42) | ((u64)__popcll(m2) << 21) | (u64)__popcll(m1);
        u64 own = p;
        for (int d = 1; d < 64; d <<= 1) {       // inclusive wave scan (packed fields)
            u64 t = __shfl_up(p, d);
            if (lane >= d) p += t;
        }
        if (lane == 63) wtot[wv] = p;
        u64 excl = p - own;
        __syncthreads();
        u64 off = carried + excl;
        for (int k = 0; k < wv; ++k) off += wtot[k];
        u32 e3 = (u32)(off >> 42);
        u32 e2 = (u32)((off >> 21) & M21);
        u32 e1 = (u32)(off & M21);
        int nb = w * 64;
        u64 mm = m3; u32 o = e3;
        while (mm) { int b2 = __builtin_ctzll(mm); mm &= mm - 1; if (o < 256) sl3[o] = nb + b2; o++; }
        mm = m2; o = e2;
        while (mm) { int b2 = __builtin_ctzll(mm); mm &= mm - 1; if (o < 256) sl2[o] = nb + b2; o++; }
        mm = m1; o = e1;
        while (mm) { int b2 = __builtin_ctzll(mm); mm &= mm - 1; if (o < 256) sl1[o] = nb + b2; o++; }
        __syncthreads();
        if (tid == 0) carried += wtot[0] + wtot[1] + wtot[2] + wtot[3];
        __syncthreads();
    }
    u64 car = carried;
    u32 t3 = (u32)(car >> 42), t2 = (u32)((car >> 21) & M21), t1 = (u32)(car & M21);
    u32 s = (u32)tid;
    int n = -1;
    if (s < t3)                 n = (int)sl3[s];
    else if (s < t3 + t2)       n = (int)sl2[s - t3];
    else if (s < t3 + t2 + t1)  n = (int)sl1[s - t3 - t2];
    float v0=0.f, v1=0.f, v2=0.f, v3=0.f, v4=0.f;
    if (n >= 0) {
        const float* pp = points + (size_t)n * 5;
        v0 = pp[0]; v1 = pp[1]; v2 = pp[2]; v3 = pp[3]; v4 = pp[4];
    }
    outg[s*5+0] = v0; outg[s*5+1] = v1; outg[s*5+2] = v2;
    outg[s*5+3] = v3; outg[s*5+4] = v4;
}

extern "C" void kernel_launch(void* const* d_in, const int* in_sizes, int n_in,
                              void* d_out, int out_size, void* d_ws, size_t ws_size,
                              hipStream_t stream)
{
    const float* points = (const float*)d_in[0];
    const float* boxes  = (const float*)d_in[1];
    const int*   labels = (const int*)d_in[2];
    const int*   pNA    = (const int*)d_in[4];
    float* out = (float*)d_out;
    char* ws = (char*)d_ws;

    u64* colbits = (u64*)ws;                                    // 3200*128*8 = 3,276,800 B
    u32* inter   = (u32*)(ws + (size_t)W64C * 128 * 8);         // 65,536 B
    int* aidx    = (int*)(ws + (size_t)W64C * 128 * 8 + 65536);

    float* out_anchor = out + (size_t)MBOX * SSAMP * 5;         // second output chunk

    kA<<<W64C / 4, 256, 0, stream>>>(points, boxes, colbits, inter);
    kB<<<(MBOX / ITILE) * NCH, 256, 0, stream>>>(colbits, inter);
    kC<<<1, 128, 0, stream>>>(inter, labels, pNA, aidx, out_anchor);
    kD<<<MBOX, 256, 0, stream>>>(colbits, aidx, points, out);
}